// Round 20
// baseline (165.533 us; speedup 1.0000x reference)
//
#include <hip/hip_runtime.h>
#include <math.h>

#define HW    4096      // 64*64
#define NCH   256       // C
#define NB    4         // batch
#define L2E   1.44269504088896340736f

typedef __attribute__((ext_vector_type(8))) short short8b;  // 8 bf16 (4 VGPRs)
typedef __attribute__((ext_vector_type(4))) float f32x4;    // 4 fp32 acc

__device__ __forceinline__ unsigned short f2bf(float f) {
    unsigned int u = __float_as_uint(f);
    u += 0x7FFFu + ((u >> 16) & 1u);          // RNE; inputs finite
    return (unsigned short)(u >> 16);
}
__device__ __forceinline__ float bf2f(unsigned short h) {
    return __uint_as_float(((unsigned int)h) << 16);
}
// pack 2 fp32 -> 2 bf16 in one instr (T12 primitive); lo = a, hi = b
__device__ __forceinline__ unsigned int cvtpk_bf16(float a, float b) {
    unsigned int r;
    asm("v_cvt_pk_bf16_f32 %0, %1, %2" : "=v"(r) : "v"(a), "v"(b));
    return r;
}

// ws layout, total 12.56 MB:
//   ebuf  fp32 [n][4096]                64 KB   (-m2 - log2(l), base-2)
//   mpart fp32 [4][n][4096]            256 KB
//   lpart fp32 [4][n][4096]            256 KB
//   r1h/r1l/r2h/r2l bf16 [n][4096][32] 4x1 MB   (hi/lo splits, [i][o])
//   vtb  bf16 [n][128][256][32]          8 MB   (V blocked: [i>>5][c][i&31])

// ---------------------------------------------------------------------------
// fused_proj: blocks 0..511 = proj_rr (fp32 VALU); blocks 512..1535 = proj_v
// (bf16 MFMA, wv converted inline).  VERBATIM R19.
// ---------------------------------------------------------------------------
__global__ __launch_bounds__(256) void fused_proj_kernel(
    const float* __restrict__ x, const float* __restrict__ w1,
    const float* __restrict__ w2, const float* __restrict__ wv,
    unsigned short* __restrict__ r1h, unsigned short* __restrict__ r1l,
    unsigned short* __restrict__ r2h, unsigned short* __restrict__ r2l,
    unsigned short* __restrict__ vtb)
{
    __shared__ float aT[16][36];            // proj_rr: [k][m 32]
    __shared__ float bS[16][68];            // proj_rr: [k][i 64]
    __shared__ unsigned short xt[64][40];   // proj_v:  [i][k] bf16

    const int t = threadIdx.x;
    const int bid = blockIdx.x;

    if (bid < 512) {
        const int i0 = (bid & 63) * 64;
        const int mh = ((bid >> 6) & 1) * 32;
        const int n  = bid >> 7;

        const int tm = t >> 4;
        const int ti = t & 15;

        const int ar = t >> 3;
        const int ak = (t & 7) * 2;
        const int gm = mh + ar;
        const float* arow = (gm < 32) ? (w1 + (size_t)gm * NCH)
                                      : (w2 + (size_t)(gm - 32) * NCH);
        const float* xb = x + (size_t)n * NCH * HW;

        float acc[2][4] = {};

        for (int kc = 0; kc < NCH; kc += 16) {
            float2 av = *reinterpret_cast<const float2*>(arow + kc + ak);
            float4 bv = *reinterpret_cast<const float4*>(
                xb + (size_t)(kc + (t >> 4)) * HW + i0 + (t & 15) * 4);
            __syncthreads();
            aT[ak + 0][ar] = av.x;
            aT[ak + 1][ar] = av.y;
            *reinterpret_cast<float4*>(&bS[t >> 4][(t & 15) * 4]) = bv;
            __syncthreads();
            #pragma unroll
            for (int kk = 0; kk < 16; ++kk) {
                float2 a2 = *reinterpret_cast<const float2*>(&aT[kk][tm * 2]);
                float4 b4 = *reinterpret_cast<const float4*>(&bS[kk][ti * 4]);
                float a[2] = {a2.x, a2.y};
                float b[4] = {b4.x, b4.y, b4.z, b4.w};
                #pragma unroll
                for (int mm = 0; mm < 2; ++mm)
                    #pragma unroll
                    for (int jj = 0; jj < 4; ++jj)
                        acc[mm][jj] = fmaf(a[mm], b[jj], acc[mm][jj]);
            }
        }

        #pragma unroll
        for (int mm = 0; mm < 2; ++mm) {
            const int m = mh + tm * 2 + mm;
            unsigned short* bhp = (m < 32) ? r1h : r2h;
            unsigned short* blp = (m < 32) ? r1l : r2l;
            const int o = m & 31;
            #pragma unroll
            for (int jj = 0; jj < 4; ++jj) {
                const int i = i0 + ti * 4 + jj;
                float v = acc[mm][jj];
                unsigned short h = f2bf(v);
                unsigned short lo = f2bf(v - bf2f(h));
                size_t idx = ((size_t)n * HW + i) * 32 + o;
                bhp[idx] = h;
                blp[idx] = lo;
            }
        }
    } else {
        const int b  = bid - 512;
        const int iB = (b & 63) * 64;
        const int cB = ((b >> 6) & 3) * 64;
        const int n  = b >> 8;
        const float* xb = x + (size_t)n * NCH * HW;

        const int w = t >> 6, l = t & 63;
        const int lj = l & 15, lg = l >> 4;
        const int iw = (w >> 1) * 32;
        const int cw = (w & 1) * 32;

        f32x4 acc[2][2] = {};

        const int kr = t >> 4;
        const int ic = (t & 15) * 4;

        for (int kc = 0; kc < NCH; kc += 32) {
            float4 x0 = *reinterpret_cast<const float4*>(
                xb + (size_t)(kc + kr) * HW + iB + ic);
            float4 x1 = *reinterpret_cast<const float4*>(
                xb + (size_t)(kc + kr + 16) * HW + iB + ic);
            __syncthreads();
            xt[ic + 0][kr] = f2bf(x0.x); xt[ic + 1][kr] = f2bf(x0.y);
            xt[ic + 2][kr] = f2bf(x0.z); xt[ic + 3][kr] = f2bf(x0.w);
            xt[ic + 0][kr + 16] = f2bf(x1.x); xt[ic + 1][kr + 16] = f2bf(x1.y);
            xt[ic + 2][kr + 16] = f2bf(x1.z); xt[ic + 3][kr + 16] = f2bf(x1.w);
            __syncthreads();

            short8b xa[2], wb[2];
            #pragma unroll
            for (int is = 0; is < 2; ++is)
                xa[is] = *reinterpret_cast<const short8b*>(
                    &xt[iw + is * 16 + lj][lg * 8]);
            #pragma unroll
            for (int cs = 0; cs < 2; ++cs) {
                const float* wrow = wv
                    + (size_t)(cB + cw + cs * 16 + lj) * NCH + kc + lg * 8;
                float4 wa = *reinterpret_cast<const float4*>(wrow);
                float4 wc = *reinterpret_cast<const float4*>(wrow + 4);
                short8b wf;
                wf[0] = (short)f2bf(wa.x); wf[1] = (short)f2bf(wa.y);
                wf[2] = (short)f2bf(wa.z); wf[3] = (short)f2bf(wa.w);
                wf[4] = (short)f2bf(wc.x); wf[5] = (short)f2bf(wc.y);
                wf[6] = (short)f2bf(wc.z); wf[7] = (short)f2bf(wc.w);
                wb[cs] = wf;
            }
            #pragma unroll
            for (int is = 0; is < 2; ++is)
                #pragma unroll
                for (int cs = 0; cs < 2; ++cs)
                    acc[is][cs] = __builtin_amdgcn_mfma_f32_16x16x32_bf16(
                        xa[is], wb[cs], acc[is][cs], 0, 0, 0);
        }

        unsigned short* op = vtb + (size_t)n * HW * 256;
        #pragma unroll
        for (int is = 0; is < 2; ++is) {
            #pragma unroll
            for (int cs = 0; cs < 2; ++cs) {
                const int c = cB + cw + cs * 16 + lj;
                #pragma unroll
                for (int r = 0; r < 4; ++r) {
                    const int i = iB + iw + is * 16 + lg * 4 + r;
                    op[(size_t)(i >> 5) * 8192 + c * 32 + (i & 31)] =
                        f2bf(acc[is][cs][r]);
                }
            }
        }
    }
}

// ---------------------------------------------------------------------------
// stats (single-pass online, base-2, DUAL-ACCUMULATOR + 2-deep prefetch):
// per row i over a j-quarter: even jt -> (mxA,smA), odd jt -> (mxB,smB);
// loads for jt+2/jt+3 issued while computing jt/jt+1.  m is exact
// (max is order-independent); sm differs only in fp summation order.
// grid (64 i-blk, 4 j-quarter, NB) = 1024 blocks, 256 thr.
// ---------------------------------------------------------------------------
__global__ __launch_bounds__(256) void stats_kernel(
    const unsigned short* __restrict__ r1h, const unsigned short* __restrict__ r1l,
    const unsigned short* __restrict__ r2h, const unsigned short* __restrict__ r2l,
    float* __restrict__ mpart, float* __restrict__ lpart)
{
    const int t = threadIdx.x;
    const int w = t >> 6, l = t & 63;
    const int lj = l & 15, lg = l >> 4;
    const int i0 = blockIdx.x * 64 + w * 16;
    const int jh = blockIdx.y * 1024;
    const int n  = blockIdx.z;
    const size_t nHW = (size_t)n * HW;

    const size_t ab = (nHW + i0 + lj) * 32 + lg * 8;
    const short8b ah = *reinterpret_cast<const short8b*>(r1h + ab);
    const short8b al = *reinterpret_cast<const short8b*>(r1l + ab);
    const size_t bbase = (nHW + jh + lj) * 32 + lg * 8;

    f32x4 mxA = {-INFINITY, -INFINITY, -INFINITY, -INFINITY};
    f32x4 smA = {0.f, 0.f, 0.f, 0.f};
    f32x4 mxB = {-INFINITY, -INFINITY, -INFINITY, -INFINITY};
    f32x4 smB = {0.f, 0.f, 0.f, 0.f};

    // 2-deep pipeline: slots 0 (even jt) and 1 (odd jt)
    short8b bh0 = *reinterpret_cast<const short8b*>(r2h + bbase);
    short8b bl0 = *reinterpret_cast<const short8b*>(r2l + bbase);
    short8b bh1 = *reinterpret_cast<const short8b*>(r2h + bbase + 512);
    short8b bl1 = *reinterpret_cast<const short8b*>(r2l + bbase + 512);

    for (int jt = 0; jt < 64; jt += 2) {
        short8b nh0 = bh0, nl0 = bl0, nh1 = bh1, nl1 = bl1;
        if (jt < 62) {   // prefetch jt+2, jt+3
            nh0 = *reinterpret_cast<const short8b*>(r2h + bbase + (size_t)(jt + 2) * 512);
            nl0 = *reinterpret_cast<const short8b*>(r2l + bbase + (size_t)(jt + 2) * 512);
            nh1 = *reinterpret_cast<const short8b*>(r2h + bbase + (size_t)(jt + 3) * 512);
            nl1 = *reinterpret_cast<const short8b*>(r2l + bbase + (size_t)(jt + 3) * 512);
        }

        // even jt -> accumulator A
        {
            f32x4 s = {0.f, 0.f, 0.f, 0.f};
            s = __builtin_amdgcn_mfma_f32_16x16x32_bf16(al, bh0, s, 0, 0, 0);
            s = __builtin_amdgcn_mfma_f32_16x16x32_bf16(ah, bl0, s, 0, 0, 0);
            s = __builtin_amdgcn_mfma_f32_16x16x32_bf16(ah, bh0, s, 0, 0, 0);
            #pragma unroll
            for (int r = 0; r < 4; ++r) {
                float s2 = s[r] * L2E;
                float mn = fmaxf(mxA[r], s2);
                smA[r] = fmaf(smA[r], __builtin_amdgcn_exp2f(mxA[r] - mn),
                              __builtin_amdgcn_exp2f(s2 - mn));
                mxA[r] = mn;
            }
        }
        // odd jt -> accumulator B (independent chain)
        {
            f32x4 s = {0.f, 0.f, 0.f, 0.f};
            s = __builtin_amdgcn_mfma_f32_16x16x32_bf16(al, bh1, s, 0, 0, 0);
            s = __builtin_amdgcn_mfma_f32_16x16x32_bf16(ah, bl1, s, 0, 0, 0);
            s = __builtin_amdgcn_mfma_f32_16x16x32_bf16(ah, bh1, s, 0, 0, 0);
            #pragma unroll
            for (int r = 0; r < 4; ++r) {
                float s2 = s[r] * L2E;
                float mn = fmaxf(mxB[r], s2);
                smB[r] = fmaf(smB[r], __builtin_amdgcn_exp2f(mxB[r] - mn),
                              __builtin_amdgcn_exp2f(s2 - mn));
                mxB[r] = mn;
            }
        }
        bh0 = nh0; bl0 = nl0; bh1 = nh1; bl1 = nl1;
    }

    // merge A and B
    f32x4 mx, sm;
    #pragma unroll
    for (int r = 0; r < 4; ++r) {
        float mn = fmaxf(mxA[r], mxB[r]);
        sm[r] = smA[r] * __builtin_amdgcn_exp2f(mxA[r] - mn)
              + smB[r] * __builtin_amdgcn_exp2f(mxB[r] - mn);
        mx[r] = mn;
    }

    // cross-lane combine over the 16-lane j-groups
    #pragma unroll
    for (int msk = 1; msk < 16; msk <<= 1) {
        #pragma unroll
        for (int r = 0; r < 4; ++r) {
            float mo = __shfl_xor(mx[r], msk, 64);
            float so = __shfl_xor(sm[r], msk, 64);
            float mn = fmaxf(mx[r], mo);
            sm[r] = sm[r] * __builtin_amdgcn_exp2f(mx[r] - mn)
                  + so    * __builtin_amdgcn_exp2f(mo    - mn);
            mx[r] = mn;
        }
    }

    if (lj == 0) {
        float* mp = mpart + ((size_t)blockIdx.y * NB + n) * HW + i0 + lg * 4;
        float* lp = lpart + ((size_t)blockIdx.y * NB + n) * HW + i0 + lg * 4;
        #pragma unroll
        for (int r = 0; r < 4; ++r) { mp[r] = mx[r]; lp[r] = sm[r]; }
    }
}

// ---------------------------------------------------------------------------
// merge 4 j-quarters (base-2): ebuf = -m2 - log2(sum l_p * 2^{m2_p - m2})
// ---------------------------------------------------------------------------
__global__ __launch_bounds__(256) void merge_kernel(
    const float* __restrict__ mpart, const float* __restrict__ lpart,
    float* __restrict__ ebuf)
{
    const int q = blockIdx.x * 256 + threadIdx.x;   // over NB*HW
    const int T = NB * HW;
    float m0 = mpart[q], m1 = mpart[T + q];
    float m2 = mpart[2 * T + q], m3 = mpart[3 * T + q];
    float m = fmaxf(fmaxf(m0, m1), fmaxf(m2, m3));
    float lsum = lpart[q]         * __builtin_amdgcn_exp2f(m0 - m)
               + lpart[T + q]     * __builtin_amdgcn_exp2f(m1 - m)
               + lpart[2 * T + q] * __builtin_amdgcn_exp2f(m2 - m)
               + lpart[3 * T + q] * __builtin_amdgcn_exp2f(m3 - m);
    ebuf[q] = -m - log2f(lsum);
}

// ---------------------------------------------------------------------------
// attn: out[n][c][j] = x + sc * sum_i V[c][i] * exp2(S[i][j]*log2e + e_i)
// VERBATIM the round-8/13/17/18/19 kernel (passed 6x at 108.4-109.1). FROZEN.
// ---------------------------------------------------------------------------
__global__ __launch_bounds__(512) void attn_kernel(
    const unsigned short* __restrict__ r1h, const unsigned short* __restrict__ r1l,
    const unsigned short* __restrict__ r2h, const unsigned short* __restrict__ r2l,
    const float* __restrict__ ebuf, const unsigned short* __restrict__ vtb,
    const float* __restrict__ x, const float* __restrict__ scale,
    float* __restrict__ out)
{
    __shared__ char pl[2][4096];   // P dbuf: [32 j][64 i] bf16, XOR-swizzled

    const int t = threadIdx.x;
    const int w = t >> 6, l = t & 63;
    const int lj = l & 15, lg = l >> 4;

    const int bid = blockIdx.x;
    const int xcd = bid & 7;
    const int n   = xcd >> 1;
    const int j0  = ((xcd & 1) * 64 + (bid >> 3)) * 32;
    const size_t nHW = (size_t)n * HW;

    const int iw = w & 3;        // S i-slice (16 rows)
    const int jw = w >> 2;       // S j-half (16 cols)

    // persistent S B-frags (r2 hi/lo at this wave's j)
    const size_t rb = (nHW + j0 + jw * 16 + lj) * 32 + lg * 8;
    const short8b bh = *reinterpret_cast<const short8b*>(r2h + rb);
    const short8b bl = *reinterpret_cast<const short8b*>(r2l + rb);

    const unsigned short* vtn = vtb + nHW * 256;
    const int swz = (lj & 7) << 4;
    const int wroff = (jw * 16 + lj) * 128 + ((iw * 32 + lg * 8) ^ swz);
    int rdo[2][2];
    #pragma unroll
    for (int jf = 0; jf < 2; ++jf)
        #pragma unroll
        for (int ks = 0; ks < 2; ++ks)
            rdo[jf][ks] = (jf * 16 + lj) * 128 + ((ks * 64 + lg * 16) ^ swz);
    const size_t vrow = (size_t)(w * 32 + lj) * 32 + lg * 8;

    const float* erow = ebuf + nHW + iw * 16 + lg * 4;

    // ---- prologue: S(0) -> pl[0]; preload A(1)/e(1) ----
    size_t abase = (nHW + iw * 16 + lj) * 32 + lg * 8;
    short8b ah = *reinterpret_cast<const short8b*>(r1h + abase);
    short8b al = *reinterpret_cast<const short8b*>(r1l + abase);
    float4 e4 = *reinterpret_cast<const float4*>(erow);
    {
        f32x4 s = {0.f, 0.f, 0.f, 0.f};
        s = __builtin_amdgcn_mfma_f32_16x16x32_bf16(al, bh, s, 0, 0, 0);
        s = __builtin_amdgcn_mfma_f32_16x16x32_bf16(ah, bl, s, 0, 0, 0);
        s = __builtin_amdgcn_mfma_f32_16x16x32_bf16(ah, bh, s, 0, 0, 0);
        float p0 = __builtin_amdgcn_exp2f(fmaf(s[0], L2E, e4.x));
        float p1 = __builtin_amdgcn_exp2f(fmaf(s[1], L2E, e4.y));
        float p2 = __builtin_amdgcn_exp2f(fmaf(s[2], L2E, e4.z));
        float p3 = __builtin_amdgcn_exp2f(fmaf(s[3], L2E, e4.w));
        *reinterpret_cast<uint2*>(&pl[0][wroff]) =
            make_uint2(cvtpk_bf16(p0, p1), cvtpk_bf16(p2, p3));
    }
    abase += 2048;
    ah = *reinterpret_cast<const short8b*>(r1h + abase);
    al = *reinterpret_cast<const short8b*>(r1l + abase);
    e4 = *reinterpret_cast<const float4*>(erow + 64);
    __syncthreads();   // pl[0] visible

    f32x4 acc[2][2] = {};   // [cfrag][jfrag]

    for (int it = 0; it < 64; ++it) {
        // V(it) loads (L2-resident) — issued first, consumed last
        const unsigned short* vb = vtn + (size_t)(it * 2) * 8192 + vrow;
        short8b va[2][2];
        #pragma unroll
        for (int cf = 0; cf < 2; ++cf)
            #pragma unroll
            for (int ks = 0; ks < 2; ++ks)
                va[cf][ks] = *reinterpret_cast<const short8b*>(
                    vb + cf * 512 + ks * 8192);

        // S(it+1): independent of PV(it)
        if (it < 63) {
            f32x4 s = {0.f, 0.f, 0.f, 0.f};
            s = __builtin_amdgcn_mfma_f32_16x16x32_bf16(al, bh, s, 0, 0, 0);
            s = __builtin_amdgcn_mfma_f32_16x16x32_bf16(ah, bl, s, 0, 0, 0);
            s = __builtin_amdgcn_mfma_f32_16x16x32_bf16(ah, bh, s, 0, 0, 0);
            float p0 = __builtin_amdgcn_exp2f(fmaf(s[0], L2E, e4.x));
            float p1 = __builtin_amdgcn_exp2f(fmaf(s[1], L2E, e4.y));
            float p2 = __builtin_amdgcn_exp2f(fmaf(s[2], L2E, e4.z));
            float p3 = __builtin_amdgcn_exp2f(fmaf(s[3], L2E, e4.w));
            *reinterpret_cast<uint2*>(&pl[(it + 1) & 1][wroff]) =
                make_uint2(cvtpk_bf16(p0, p1), cvtpk_bf16(p2, p3));
            if (it < 62) {   // prefetch A(it+2), e(it+2)
                abase += 2048;
                ah = *reinterpret_cast<const short8b*>(r1h + abase);
                al = *reinterpret_cast<const short8b*>(r1l + abase);
                e4 = *reinterpret_cast<const float4*>(erow + (it + 2) * 64);
            }
        }

        // PV(it): read P(it) from pl[it&1], 8 MFMAs
        short8b pb[2][2];
        #pragma unroll
        for (int jf = 0; jf < 2; ++jf)
            #pragma unroll
            for (int ks = 0; ks < 2; ++ks)
                pb[jf][ks] = *reinterpret_cast<const short8b*>(
                    &pl[it & 1][rdo[jf][ks]]);
        #pragma unroll
        for (int cf = 0; cf < 2; ++cf)
            #pragma unroll
            for (int jf = 0; jf < 2; ++jf) {
                acc[cf][jf] = __builtin_amdgcn_mfma_f32_16x16x32_bf16(
                    va[cf][0], pb[jf][0], acc[cf][jf], 0, 0, 0);
                acc[cf][jf] = __builtin_amdgcn_mfma_f32_16x16x32_bf16(
                    va[cf][1], pb[jf][1], acc[cf][jf], 0, 0, 0);
            }
        __syncthreads();   // P(it+1) published; pl[it&1] reads complete
    }

    // epilogue: out = x + sc * attn
    const float sc = scale[0];
    const float* xb = x   + nHW * NCH;
    float*       ob = out + nHW * NCH;
    #pragma unroll
    for (int cf = 0; cf < 2; ++cf) {
        #pragma unroll
        for (int jf = 0; jf < 2; ++jf) {
            const int cb = w * 32 + cf * 16 + lg * 4;
            const int j  = j0 + jf * 16 + lj;
            #pragma unroll
            for (int r = 0; r < 4; ++r) {
                size_t off = (size_t)(cb + r) * HW + j;
                ob[off] = xb[off] + sc * acc[cf][jf][r];
            }
        }
    }
}

extern "C" void kernel_launch(void* const* d_in, const int* in_sizes, int n_in,
                              void* d_out, int out_size, void* d_ws, size_t ws_size,
                              hipStream_t stream) {
    (void)in_sizes; (void)n_in; (void)out_size; (void)ws_size;
    const float* x  = (const float*)d_in[0];
    const float* w1 = (const float*)d_in[1];
    const float* w2 = (const float*)d_in[2];
    const float* wv = (const float*)d_in[3];
    const float* sc = (const float*)d_in[4];
    float* out = (float*)d_out;

    float* ebuf  = (float*)d_ws;                         // 16,384 fl
    float* mpart = ebuf + (size_t)NB * HW;               // 65,536 fl
    float* lpart = mpart + (size_t)4 * NB * HW;          // 65,536 fl
    unsigned short* r1h = (unsigned short*)(lpart + (size_t)4 * NB * HW);
    unsigned short* r1l = r1h + (size_t)NB * HW * 32;    // each 524,288 ush
    unsigned short* r2h = r1l + (size_t)NB * HW * 32;
    unsigned short* r2l = r2h + (size_t)NB * HW * 32;
    unsigned short* vtb = r2l + (size_t)NB * HW * 32;    // 4,194,304 ush (8 MB)

    fused_proj_kernel<<<dim3(1536), 256, 0, stream>>>(
        x, w1, w2, wv, r1h, r1l, r2h, r2l, vtb);
    stats_kernel<<<dim3(64, 4, NB), 256, 0, stream>>>(r1h, r1l, r2h, r2l,
                                                      mpart, lpart);
    merge_kernel<<<dim3(NB * HW / 256), 256, 0, stream>>>(mpart, lpart, ebuf);
    attn_kernel<<<dim3(512), 512, 0, stream>>>(
        r1h, r1l, r2h, r2l, ebuf, vtb, x, sc, out);
}

// Round 21
// 161.315 us; speedup vs baseline: 1.0261x; 1.0261x over previous
//
#include <hip/hip_runtime.h>
#include <math.h>

#define HW    4096      // 64*64
#define NCH   256       // C
#define NB    4         // batch
#define L2E   1.44269504088896340736f

typedef __attribute__((ext_vector_type(8))) short short8b;  // 8 bf16 (4 VGPRs)
typedef __attribute__((ext_vector_type(4))) float f32x4;    // 4 fp32 acc

__device__ __forceinline__ unsigned short f2bf(float f) {
    unsigned int u = __float_as_uint(f);
    u += 0x7FFFu + ((u >> 16) & 1u);          // RNE; inputs finite
    return (unsigned short)(u >> 16);
}
__device__ __forceinline__ float bf2f(unsigned short h) {
    return __uint_as_float(((unsigned int)h) << 16);
}
// pack 2 fp32 -> 2 bf16 in one instr (T12 primitive); lo = a, hi = b
__device__ __forceinline__ unsigned int cvtpk_bf16(float a, float b) {
    unsigned int r;
    asm("v_cvt_pk_bf16_f32 %0, %1, %2" : "=v"(r) : "v"(a), "v"(b));
    return r;
}

// ws layout, total 12.56 MB:
//   ebuf  fp32 [n][4096]                64 KB   (-m2 - log2(l), base-2)
//   mpart fp32 [4][n][4096]            256 KB
//   lpart fp32 [4][n][4096]            256 KB
//   r1h/r1l/r2h/r2l bf16 [n][4096][32] 4x1 MB   (hi/lo splits, [i][o])
//   vtb  bf16 [n][128][256][32]          8 MB   (V blocked: [i>>5][c][i&31])

// ---------------------------------------------------------------------------
// fused_proj: blocks 0..511 = proj_rr (fp32 VALU); blocks 512..1535 = proj_v
// (bf16 MFMA, wv converted inline — no wvb pre-pass).  Independent work
// co-resident -> VALU/MFMA waves overlap (m114); launch count minimized.
// ---------------------------------------------------------------------------
__global__ __launch_bounds__(256) void fused_proj_kernel(
    const float* __restrict__ x, const float* __restrict__ w1,
    const float* __restrict__ w2, const float* __restrict__ wv,
    unsigned short* __restrict__ r1h, unsigned short* __restrict__ r1l,
    unsigned short* __restrict__ r2h, unsigned short* __restrict__ r2l,
    unsigned short* __restrict__ vtb)
{
    __shared__ float aT[16][36];            // proj_rr: [k][m 32]
    __shared__ float bS[16][68];            // proj_rr: [k][i 64]
    __shared__ unsigned short xt[64][40];   // proj_v:  [i][k] bf16

    const int t = threadIdx.x;
    const int bid = blockIdx.x;

    if (bid < 512) {
        // ---------------- proj_rr body, grid (64,2,NB) ---------------------
        const int i0 = (bid & 63) * 64;
        const int mh = ((bid >> 6) & 1) * 32;
        const int n  = bid >> 7;

        const int tm = t >> 4;
        const int ti = t & 15;

        const int ar = t >> 3;
        const int ak = (t & 7) * 2;
        const int gm = mh + ar;
        const float* arow = (gm < 32) ? (w1 + (size_t)gm * NCH)
                                      : (w2 + (size_t)(gm - 32) * NCH);
        const float* xb = x + (size_t)n * NCH * HW;

        float acc[2][4] = {};

        for (int kc = 0; kc < NCH; kc += 16) {
            float2 av = *reinterpret_cast<const float2*>(arow + kc + ak);
            float4 bv = *reinterpret_cast<const float4*>(
                xb + (size_t)(kc + (t >> 4)) * HW + i0 + (t & 15) * 4);
            __syncthreads();
            aT[ak + 0][ar] = av.x;
            aT[ak + 1][ar] = av.y;
            *reinterpret_cast<float4*>(&bS[t >> 4][(t & 15) * 4]) = bv;
            __syncthreads();
            #pragma unroll
            for (int kk = 0; kk < 16; ++kk) {
                float2 a2 = *reinterpret_cast<const float2*>(&aT[kk][tm * 2]);
                float4 b4 = *reinterpret_cast<const float4*>(&bS[kk][ti * 4]);
                float a[2] = {a2.x, a2.y};
                float b[4] = {b4.x, b4.y, b4.z, b4.w};
                #pragma unroll
                for (int mm = 0; mm < 2; ++mm)
                    #pragma unroll
                    for (int jj = 0; jj < 4; ++jj)
                        acc[mm][jj] = fmaf(a[mm], b[jj], acc[mm][jj]);
            }
        }

        #pragma unroll
        for (int mm = 0; mm < 2; ++mm) {
            const int m = mh + tm * 2 + mm;
            unsigned short* bhp = (m < 32) ? r1h : r2h;
            unsigned short* blp = (m < 32) ? r1l : r2l;
            const int o = m & 31;
            #pragma unroll
            for (int jj = 0; jj < 4; ++jj) {
                const int i = i0 + ti * 4 + jj;
                float v = acc[mm][jj];
                unsigned short h = f2bf(v);
                unsigned short lo = f2bf(v - bf2f(h));
                size_t idx = ((size_t)n * HW + i) * 32 + o;
                bhp[idx] = h;
                blp[idx] = lo;
            }
        }
    } else {
        // ------------- proj_v body (inline wv conversion) ------------------
        const int b  = bid - 512;
        const int iB = (b & 63) * 64;
        const int cB = ((b >> 6) & 3) * 64;
        const int n  = b >> 8;
        const float* xb = x + (size_t)n * NCH * HW;

        const int w = t >> 6, l = t & 63;
        const int lj = l & 15, lg = l >> 4;
        const int iw = (w >> 1) * 32;
        const int cw = (w & 1) * 32;

        f32x4 acc[2][2] = {};

        const int kr = t >> 4;
        const int ic = (t & 15) * 4;

        for (int kc = 0; kc < NCH; kc += 32) {
            float4 x0 = *reinterpret_cast<const float4*>(
                xb + (size_t)(kc + kr) * HW + iB + ic);
            float4 x1 = *reinterpret_cast<const float4*>(
                xb + (size_t)(kc + kr + 16) * HW + iB + ic);
            __syncthreads();
            xt[ic + 0][kr] = f2bf(x0.x); xt[ic + 1][kr] = f2bf(x0.y);
            xt[ic + 2][kr] = f2bf(x0.z); xt[ic + 3][kr] = f2bf(x0.w);
            xt[ic + 0][kr + 16] = f2bf(x1.x); xt[ic + 1][kr + 16] = f2bf(x1.y);
            xt[ic + 2][kr + 16] = f2bf(x1.z); xt[ic + 3][kr + 16] = f2bf(x1.w);
            __syncthreads();

            short8b xa[2], wb[2];
            #pragma unroll
            for (int is = 0; is < 2; ++is)
                xa[is] = *reinterpret_cast<const short8b*>(
                    &xt[iw + is * 16 + lj][lg * 8]);
            #pragma unroll
            for (int cs = 0; cs < 2; ++cs) {
                const float* wrow = wv
                    + (size_t)(cB + cw + cs * 16 + lj) * NCH + kc + lg * 8;
                float4 wa = *reinterpret_cast<const float4*>(wrow);
                float4 wc = *reinterpret_cast<const float4*>(wrow + 4);
                short8b wf;
                wf[0] = (short)f2bf(wa.x); wf[1] = (short)f2bf(wa.y);
                wf[2] = (short)f2bf(wa.z); wf[3] = (short)f2bf(wa.w);
                wf[4] = (short)f2bf(wc.x); wf[5] = (short)f2bf(wc.y);
                wf[6] = (short)f2bf(wc.z); wf[7] = (short)f2bf(wc.w);
                wb[cs] = wf;
            }
            #pragma unroll
            for (int is = 0; is < 2; ++is)
                #pragma unroll
                for (int cs = 0; cs < 2; ++cs)
                    acc[is][cs] = __builtin_amdgcn_mfma_f32_16x16x32_bf16(
                        xa[is], wb[cs], acc[is][cs], 0, 0, 0);
        }

        unsigned short* op = vtb + (size_t)n * HW * 256;
        #pragma unroll
        for (int is = 0; is < 2; ++is) {
            #pragma unroll
            for (int cs = 0; cs < 2; ++cs) {
                const int c = cB + cw + cs * 16 + lj;
                #pragma unroll
                for (int r = 0; r < 4; ++r) {
                    const int i = iB + iw + is * 16 + lg * 4 + r;
                    op[(size_t)(i >> 5) * 8192 + c * 32 + (i & 31)] =
                        f2bf(acc[is][cs][r]);
                }
            }
        }
    }
}

// ---------------------------------------------------------------------------
// stats (single-pass online, base-2): per row i over a j-quarter (1024 j):
// running m2 = max(S*log2e), sm = sum exp2(S*log2e - m2), rescaled online.
// grid (64 i-blk, 4 j-quarter, NB) = 1024 blocks, 256 thr.  (R13/R19 verbatim)
// ---------------------------------------------------------------------------
__global__ __launch_bounds__(256) void stats_kernel(
    const unsigned short* __restrict__ r1h, const unsigned short* __restrict__ r1l,
    const unsigned short* __restrict__ r2h, const unsigned short* __restrict__ r2l,
    float* __restrict__ mpart, float* __restrict__ lpart)
{
    const int t = threadIdx.x;
    const int w = t >> 6, l = t & 63;
    const int lj = l & 15, lg = l >> 4;
    const int i0 = blockIdx.x * 64 + w * 16;
    const int jh = blockIdx.y * 1024;
    const int n  = blockIdx.z;
    const size_t nHW = (size_t)n * HW;

    const size_t ab = (nHW + i0 + lj) * 32 + lg * 8;
    const short8b ah = *reinterpret_cast<const short8b*>(r1h + ab);
    const short8b al = *reinterpret_cast<const short8b*>(r1l + ab);
    const size_t bbase = (nHW + jh + lj) * 32 + lg * 8;

    f32x4 mx = {-INFINITY, -INFINITY, -INFINITY, -INFINITY};   // base-2 max
    f32x4 sm = {0.f, 0.f, 0.f, 0.f};

    short8b bh = *reinterpret_cast<const short8b*>(r2h + bbase);
    short8b bl = *reinterpret_cast<const short8b*>(r2l + bbase);
    for (int jt = 0; jt < 64; ++jt) {
        short8b nh = bh, nl = bl;
        if (jt < 63) {
            nh = *reinterpret_cast<const short8b*>(r2h + bbase + (size_t)(jt + 1) * 512);
            nl = *reinterpret_cast<const short8b*>(r2l + bbase + (size_t)(jt + 1) * 512);
        }
        f32x4 s = {0.f, 0.f, 0.f, 0.f};
        s = __builtin_amdgcn_mfma_f32_16x16x32_bf16(al, bh, s, 0, 0, 0);
        s = __builtin_amdgcn_mfma_f32_16x16x32_bf16(ah, bl, s, 0, 0, 0);
        s = __builtin_amdgcn_mfma_f32_16x16x32_bf16(ah, bh, s, 0, 0, 0);
        #pragma unroll
        for (int r = 0; r < 4; ++r) {
            float s2 = s[r] * L2E;
            float mn = fmaxf(mx[r], s2);
            sm[r] = fmaf(sm[r], __builtin_amdgcn_exp2f(mx[r] - mn),
                         __builtin_amdgcn_exp2f(s2 - mn));
            mx[r] = mn;
        }
        bh = nh; bl = nl;
    }

    // cross-lane combine over the 16-lane j-groups
    #pragma unroll
    for (int msk = 1; msk < 16; msk <<= 1) {
        #pragma unroll
        for (int r = 0; r < 4; ++r) {
            float mo = __shfl_xor(mx[r], msk, 64);
            float so = __shfl_xor(sm[r], msk, 64);
            float mn = fmaxf(mx[r], mo);
            sm[r] = sm[r] * __builtin_amdgcn_exp2f(mx[r] - mn)
                  + so    * __builtin_amdgcn_exp2f(mo    - mn);
            mx[r] = mn;
        }
    }

    if (lj == 0) {
        float* mp = mpart + ((size_t)blockIdx.y * NB + n) * HW + i0 + lg * 4;
        float* lp = lpart + ((size_t)blockIdx.y * NB + n) * HW + i0 + lg * 4;
        #pragma unroll
        for (int r = 0; r < 4; ++r) { mp[r] = mx[r]; lp[r] = sm[r]; }
    }
}

// ---------------------------------------------------------------------------
// merge 4 j-quarters (base-2): ebuf = -m2 - log2(sum l_p * 2^{m2_p - m2})
// ---------------------------------------------------------------------------
__global__ __launch_bounds__(256) void merge_kernel(
    const float* __restrict__ mpart, const float* __restrict__ lpart,
    float* __restrict__ ebuf)
{
    const int q = blockIdx.x * 256 + threadIdx.x;   // over NB*HW
    const int T = NB * HW;
    float m0 = mpart[q], m1 = mpart[T + q];
    float m2 = mpart[2 * T + q], m3 = mpart[3 * T + q];
    float m = fmaxf(fmaxf(m0, m1), fmaxf(m2, m3));
    float lsum = lpart[q]         * __builtin_amdgcn_exp2f(m0 - m)
               + lpart[T + q]     * __builtin_amdgcn_exp2f(m1 - m)
               + lpart[2 * T + q] * __builtin_amdgcn_exp2f(m2 - m)
               + lpart[3 * T + q] * __builtin_amdgcn_exp2f(m3 - m);
    ebuf[q] = -m - log2f(lsum);
}

// ---------------------------------------------------------------------------
// attn: out[n][c][j] = x + sc * sum_i V[c][i] * exp2(S[i][j]*log2e + e_i)
// VERBATIM the round-8/13/17/18/19/20 kernel (passed 7x at 108.2-109.1 us).
// grid 512 linear blocks, 512 thr (8 waves).  XCD-aware: xcd = bid&7 hosts
// n = xcd>>1.  Tile 32 j x 256 c; i-steps of 64.  Wave (iw=w&3, jw=w>>2):
// S frag (16i x 16j); PV: wave covers c w*32..+32, both j-halves.
// P dbuf 8 KB LDS; pipeline S(it+1) over PV(it); one barrier/iter.
// ---------------------------------------------------------------------------
__global__ __launch_bounds__(512) void attn_kernel(
    const unsigned short* __restrict__ r1h, const unsigned short* __restrict__ r1l,
    const unsigned short* __restrict__ r2h, const unsigned short* __restrict__ r2l,
    const float* __restrict__ ebuf, const unsigned short* __restrict__ vtb,
    const float* __restrict__ x, const float* __restrict__ scale,
    float* __restrict__ out)
{
    __shared__ char pl[2][4096];   // P dbuf: [32 j][64 i] bf16, XOR-swizzled

    const int t = threadIdx.x;
    const int w = t >> 6, l = t & 63;
    const int lj = l & 15, lg = l >> 4;

    const int bid = blockIdx.x;
    const int xcd = bid & 7;
    const int n   = xcd >> 1;
    const int j0  = ((xcd & 1) * 64 + (bid >> 3)) * 32;
    const size_t nHW = (size_t)n * HW;

    const int iw = w & 3;        // S i-slice (16 rows)
    const int jw = w >> 2;       // S j-half (16 cols)

    // persistent S B-frags (r2 hi/lo at this wave's j)
    const size_t rb = (nHW + j0 + jw * 16 + lj) * 32 + lg * 8;
    const short8b bh = *reinterpret_cast<const short8b*>(r2h + rb);
    const short8b bl = *reinterpret_cast<const short8b*>(r2l + rb);

    const unsigned short* vtn = vtb + nHW * 256;
    const int swz = (lj & 7) << 4;
    const int wroff = (jw * 16 + lj) * 128 + ((iw * 32 + lg * 8) ^ swz);
    int rdo[2][2];
    #pragma unroll
    for (int jf = 0; jf < 2; ++jf)
        #pragma unroll
        for (int ks = 0; ks < 2; ++ks)
            rdo[jf][ks] = (jf * 16 + lj) * 128 + ((ks * 64 + lg * 16) ^ swz);
    const size_t vrow = (size_t)(w * 32 + lj) * 32 + lg * 8;

    const float* erow = ebuf + nHW + iw * 16 + lg * 4;

    // ---- prologue: S(0) -> pl[0]; preload A(1)/e(1) ----
    size_t abase = (nHW + iw * 16 + lj) * 32 + lg * 8;
    short8b ah = *reinterpret_cast<const short8b*>(r1h + abase);
    short8b al = *reinterpret_cast<const short8b*>(r1l + abase);
    float4 e4 = *reinterpret_cast<const float4*>(erow);
    {
        f32x4 s = {0.f, 0.f, 0.f, 0.f};
        s = __builtin_amdgcn_mfma_f32_16x16x32_bf16(al, bh, s, 0, 0, 0);
        s = __builtin_amdgcn_mfma_f32_16x16x32_bf16(ah, bl, s, 0, 0, 0);
        s = __builtin_amdgcn_mfma_f32_16x16x32_bf16(ah, bh, s, 0, 0, 0);
        float p0 = __builtin_amdgcn_exp2f(fmaf(s[0], L2E, e4.x));
        float p1 = __builtin_amdgcn_exp2f(fmaf(s[1], L2E, e4.y));
        float p2 = __builtin_amdgcn_exp2f(fmaf(s[2], L2E, e4.z));
        float p3 = __builtin_amdgcn_exp2f(fmaf(s[3], L2E, e4.w));
        *reinterpret_cast<uint2*>(&pl[0][wroff]) =
            make_uint2(cvtpk_bf16(p0, p1), cvtpk_bf16(p2, p3));
    }
    abase += 2048;
    ah = *reinterpret_cast<const short8b*>(r1h + abase);
    al = *reinterpret_cast<const short8b*>(r1l + abase);
    e4 = *reinterpret_cast<const float4*>(erow + 64);
    __syncthreads();   // pl[0] visible

    f32x4 acc[2][2] = {};   // [cfrag][jfrag]

    for (int it = 0; it < 64; ++it) {
        // V(it) loads (L2-resident) — issued first, consumed last
        const unsigned short* vb = vtn + (size_t)(it * 2) * 8192 + vrow;
        short8b va[2][2];
        #pragma unroll
        for (int cf = 0; cf < 2; ++cf)
            #pragma unroll
            for (int ks = 0; ks < 2; ++ks)
                va[cf][ks] = *reinterpret_cast<const short8b*>(
                    vb + cf * 512 + ks * 8192);

        // S(it+1): independent of PV(it)
        if (it < 63) {
            f32x4 s = {0.f, 0.f, 0.f, 0.f};
            s = __builtin_amdgcn_mfma_f32_16x16x32_bf16(al, bh, s, 0, 0, 0);
            s = __builtin_amdgcn_mfma_f32_16x16x32_bf16(ah, bl, s, 0, 0, 0);
            s = __builtin_amdgcn_mfma_f32_16x16x32_bf16(ah, bh, s, 0, 0, 0);
            float p0 = __builtin_amdgcn_exp2f(fmaf(s[0], L2E, e4.x));
            float p1 = __builtin_amdgcn_exp2f(fmaf(s[1], L2E, e4.y));
            float p2 = __builtin_amdgcn_exp2f(fmaf(s[2], L2E, e4.z));
            float p3 = __builtin_amdgcn_exp2f(fmaf(s[3], L2E, e4.w));
            *reinterpret_cast<uint2*>(&pl[(it + 1) & 1][wroff]) =
                make_uint2(cvtpk_bf16(p0, p1), cvtpk_bf16(p2, p3));
            if (it < 62) {   // prefetch A(it+2), e(it+2)
                abase += 2048;
                ah = *reinterpret_cast<const short8b*>(r1h + abase);
                al = *reinterpret_cast<const short8b*>(r1l + abase);
                e4 = *reinterpret_cast<const float4*>(erow + (it + 2) * 64);
            }
        }

        // PV(it): read P(it) from pl[it&1], 8 MFMAs
        short8b pb[2][2];
        #pragma unroll
        for (int jf = 0; jf < 2; ++jf)
            #pragma unroll
            for (int ks = 0; ks < 2; ++ks)
                pb[jf][ks] = *reinterpret_cast<const short8b*>(
                    &pl[it & 1][rdo[jf][ks]]);
        #pragma unroll
        for (int cf = 0; cf < 2; ++cf)
            #pragma unroll
            for (int jf = 0; jf < 2; ++jf) {
                acc[cf][jf] = __builtin_amdgcn_mfma_f32_16x16x32_bf16(
                    va[cf][0], pb[jf][0], acc[cf][jf], 0, 0, 0);
                acc[cf][jf] = __builtin_amdgcn_mfma_f32_16x16x32_bf16(
                    va[cf][1], pb[jf][1], acc[cf][jf], 0, 0, 0);
            }
        __syncthreads();   // P(it+1) published; pl[it&1] reads complete
    }

    // epilogue: out = x + sc * attn
    const float sc = scale[0];
    const float* xb = x   + nHW * NCH;
    float*       ob = out + nHW * NCH;
    #pragma unroll
    for (int cf = 0; cf < 2; ++cf) {
        #pragma unroll
        for (int jf = 0; jf < 2; ++jf) {
            const int cb = w * 32 + cf * 16 + lg * 4;
            const int j  = j0 + jf * 16 + lj;
            #pragma unroll
            for (int r = 0; r < 4; ++r) {
                size_t off = (size_t)(cb + r) * HW + j;
                ob[off] = xb[off] + sc * acc[cf][jf][r];
            }
        }
    }
}

extern "C" void kernel_launch(void* const* d_in, const int* in_sizes, int n_in,
                              void* d_out, int out_size, void* d_ws, size_t ws_size,
                              hipStream_t stream) {
    (void)in_sizes; (void)n_in; (void)out_size; (void)ws_size;
    const float* x  = (const float*)d_in[0];
    const float* w1 = (const float*)d_in[1];
    const float* w2 = (const float*)d_in[2];
    const float* wv = (const float*)d_in[3];
    const float* sc = (const float*)d_in[4];
    float* out = (float*)d_out;

    float* ebuf  = (float*)d_ws;                         // 16,384 fl
    float* mpart = ebuf + (size_t)NB * HW;               // 65,536 fl
    float* lpart = mpart + (size_t)4 * NB * HW;          // 65,536 fl
    unsigned short* r1h = (unsigned short*)(lpart + (size_t)4 * NB * HW);
    unsigned short* r1l = r1h + (size_t)NB * HW * 32;    // each 524,288 ush
    unsigned short* r2h = r1l + (size_t)NB * HW * 32;
    unsigned short* r2l = r2h + (size_t)NB * HW * 32;
    unsigned short* vtb = r2l + (size_t)NB * HW * 32;    // 4,194,304 ush (8 MB)

    fused_proj_kernel<<<dim3(1536), 256, 0, stream>>>(
        x, w1, w2, wv, r1h, r1l, r2h, r2l, vtb);
    stats_kernel<<<dim3(64, 4, NB), 256, 0, stream>>>(r1h, r1l, r2h, r2l,
                                                      mpart, lpart);
    merge_kernel<<<dim3(NB * HW / 256), 256, 0, stream>>>(mpart, lpart, ebuf);
    attn_kernel<<<dim3(512), 512, 0, stream>>>(
        r1h, r1l, r2h, r2l, ebuf, vtb, x, sc, out);
}